// Round 1
// baseline (461.775 us; speedup 1.0000x reference)
//
#include <hip/hip_runtime.h>

#define B_ 4
#define C_ 64
#define H_ 128
#define W_ 128
#define O_ 64
#define KK_ 9
#define OFFC_ 18
#define HW_ (H_*W_)

// ---------------- kernel 1: 3x3 offset conv (64 -> 18 ch) ----------------
// one thread per (b,h,w); computes all 18 output channels so x loads
// amortize 18x and weight loads are wave-uniform (scalar loads).
__global__ __launch_bounds__(256) void k_offset_conv(
    const float* __restrict__ x, const float* __restrict__ w_off,
    const float* __restrict__ b_off, float* __restrict__ offs)
{
    int idx = blockIdx.x * 256 + threadIdx.x;   // 4*128*128 = 65536 total
    int w = idx & (W_ - 1);
    int h = (idx >> 7) & (H_ - 1);
    int b = idx >> 14;
    float acc[OFFC_];
#pragma unroll
    for (int co = 0; co < OFFC_; ++co) acc[co] = b_off[co];
    const float* xb = x + b * C_ * HW_;
    for (int c = 0; c < C_; ++c) {
        const float* xc = xb + c * HW_;
#pragma unroll
        for (int ky = 0; ky < 3; ++ky) {
            int y = h + ky - 1;
            if ((unsigned)y >= (unsigned)H_) continue;
#pragma unroll
            for (int kx = 0; kx < 3; ++kx) {
                int xx = w + kx - 1;
                if ((unsigned)xx >= (unsigned)W_) continue;
                float xv = xc[y * W_ + xx];
#pragma unroll
                for (int co = 0; co < OFFC_; ++co)
                    acc[co] += xv * w_off[(co * C_ + c) * 9 + ky * 3 + kx];
            }
        }
    }
#pragma unroll
    for (int co = 0; co < OFFC_; ++co)
        offs[((b * OFFC_ + co) * H_ + h) * W_ + w] = acc[co];
}

// ---------------- kernel 1b: permute w_dcn [o][c][kk] -> [o][kk][c] ----------------
__global__ __launch_bounds__(256) void k_permute_w(
    const float* __restrict__ w_dcn, float* __restrict__ wp)
{
    int i = blockIdx.x * 256 + threadIdx.x;     // 64*64*9 = 36864
    if (i >= O_ * C_ * KK_) return;
    int kk = i % 9;
    int c  = (i / 9) % C_;
    int o  = i / (C_ * 9);
    wp[o * 576 + kk * 64 + c] = w_dcn[i];
}

// ---------------- kernel 2: deformable conv ----------------
// one block = 16 consecutive pixels of one output row.
#define TP 16
#define VS 580   // per-pixel val stride in floats (576 + 4: 16B-aligned, offsets bank phase)

__global__ __launch_bounds__(256) void k_deform(
    const float* __restrict__ x, const float* __restrict__ offs,
    const float* __restrict__ wp, const float* __restrict__ b_dcn,
    float* __restrict__ out)
{
    __shared__ float val[TP * VS];          // 37120 B
    __shared__ float pos[TP][KK_][4];       // fy, fx, ly, lx

    int tid = threadIdx.x;
    int blk = blockIdx.x;
    int wt = blk & 7;               // W/TP = 8
    int ho = (blk >> 3) & (H_ - 1);
    int b  = blk >> 10;
    int wo0 = wt * TP;

    // ---- phase A: sampling positions for 16 pixels x 9 taps ----
    if (tid < TP * KK_) {
        int p  = tid / KK_;
        int kk = tid % KK_;
        int wo = wo0 + p;
        int ki = kk / 3, kj = kk % 3;
        float dy = offs[((b * OFFC_ + 2 * kk    ) * H_ + ho) * W_ + wo];
        float dx = offs[((b * OFFC_ + 2 * kk + 1) * H_ + ho) * W_ + wo];
        float py = (float)(ho - 1 + ki) + dy;
        float px = (float)(wo - 1 + kj) + dx;
        float fy = floorf(py), fx = floorf(px);
        pos[p][kk][0] = fy;
        pos[p][kk][1] = fx;
        pos[p][kk][2] = py - fy;
        pos[p][kk][3] = px - fx;
    }
    __syncthreads();

    // ---- phase B: bilinear gather -> val[p][kk][c] ----
    {
        int p  = tid & 15;          // pixel fastest across lanes -> coalesced x reads
        int cg = tid >> 4;          // channel group, 4 channels each
        const float* xb = x + b * C_ * HW_ + (cg * 4) * HW_;
        for (int kk = 0; kk < KK_; ++kk) {
            float fy = pos[p][kk][0], fx = pos[p][kk][1];
            float ly = pos[p][kk][2], lx = pos[p][kk][3];
            int y0 = (int)fy, x0 = (int)fx;
            int y1 = y0 + 1,  x1 = x0 + 1;
            float my0 = (y0 >= 0 && y0 < H_) ? 1.f : 0.f;
            float my1 = (y1 >= 0 && y1 < H_) ? 1.f : 0.f;
            float mx0 = (x0 >= 0 && x0 < W_) ? 1.f : 0.f;
            float mx1 = (x1 >= 0 && x1 < W_) ? 1.f : 0.f;
            int y0c = min(max(y0, 0), H_ - 1), y1c = min(max(y1, 0), H_ - 1);
            int x0c = min(max(x0, 0), W_ - 1), x1c = min(max(x1, 0), W_ - 1);
            int o00 = y0c * W_ + x0c, o01 = y0c * W_ + x1c;
            int o10 = y1c * W_ + x0c, o11 = y1c * W_ + x1c;
            float wy1 = ly, wy0 = 1.f - ly, wx1 = lx, wx0 = 1.f - lx;
            float w00 = wy0 * wx0 * my0 * mx0;
            float w01 = wy0 * wx1 * my0 * mx1;
            float w10 = wy1 * wx0 * my1 * mx0;
            float w11 = wy1 * wx1 * my1 * mx1;
#pragma unroll
            for (int ci = 0; ci < 4; ++ci) {
                const float* xc = xb + ci * HW_;
                float v = w00 * xc[o00] + w01 * xc[o01]
                        + w10 * xc[o10] + w11 * xc[o11];
                val[p * VS + kk * 64 + cg * 4 + ci] = v;
            }
        }
    }
    __syncthreads();

    // ---- phase C: GEMV out[o][p] = sum_i wp[o][i] * val[p][i] ----
    {
        int o  = tid & 63;          // whole wave shares pg -> LDS broadcast reads
        int pg = tid >> 6;          // 4 pixels per thread
        const float4* wrow = (const float4*)(wp + o * 576);
        const float4* v0 = (const float4*)(val + (pg * 4 + 0) * VS);
        const float4* v1 = (const float4*)(val + (pg * 4 + 1) * VS);
        const float4* v2 = (const float4*)(val + (pg * 4 + 2) * VS);
        const float4* v3 = (const float4*)(val + (pg * 4 + 3) * VS);
        float acc0 = 0.f, acc1 = 0.f, acc2 = 0.f, acc3 = 0.f;
        for (int i = 0; i < 144; ++i) {
            float4 wv = wrow[i];
            float4 a = v0[i], bq = v1[i], cq = v2[i], dq = v3[i];
            acc0 += wv.x * a.x  + wv.y * a.y  + wv.z * a.z  + wv.w * a.w;
            acc1 += wv.x * bq.x + wv.y * bq.y + wv.z * bq.z + wv.w * bq.w;
            acc2 += wv.x * cq.x + wv.y * cq.y + wv.z * cq.z + wv.w * cq.w;
            acc3 += wv.x * dq.x + wv.y * dq.y + wv.z * dq.z + wv.w * dq.w;
        }
        float bias = b_dcn[o];
        float* op = out + ((b * O_ + o) * H_ + ho) * W_ + wo0 + pg * 4;
        *(float4*)op = make_float4(acc0 + bias, acc1 + bias, acc2 + bias, acc3 + bias);
    }
}

extern "C" void kernel_launch(void* const* d_in, const int* in_sizes, int n_in,
                              void* d_out, int out_size, void* d_ws, size_t ws_size,
                              hipStream_t stream) {
    const float* x     = (const float*)d_in[0];
    const float* w_off = (const float*)d_in[1];
    const float* b_off = (const float*)d_in[2];
    const float* w_dcn = (const float*)d_in[3];
    const float* b_dcn = (const float*)d_in[4];
    float* out = (float*)d_out;

    float* offs = (float*)d_ws;                         // 4*18*128*128 floats = 4.72 MB
    float* wp   = offs + (size_t)B_ * OFFC_ * HW_;      // 36864 floats

    k_offset_conv<<<B_ * HW_ / 256, 256, 0, stream>>>(x, w_off, b_off, offs);
    k_permute_w<<<(O_ * C_ * KK_ + 255) / 256, 256, 0, stream>>>(w_dcn, wp);
    k_deform<<<B_ * H_ * (W_ / TP), 256, 0, stream>>>(x, offs, wp, b_dcn, out);
}

// Round 2
// 91.124 us; speedup vs baseline: 5.0675x; 5.0675x over previous
//
#include <hip/hip_runtime.h>

#define B_ 4
#define C_ 64
#define H_ 128
#define W_ 128
#define O_ 64
#define KK_ 9
#define OFFC_ 18
#define HW_ (H_*W_)
#define VSB 1152   // val row stride in bytes (576 bf16)

typedef __attribute__((ext_vector_type(8))) short bs8;
typedef __attribute__((ext_vector_type(4))) float f32x4;

static __device__ __forceinline__ unsigned short f2bf(float f) {
    union { float f; unsigned u; } v; v.f = f;
    unsigned r = v.u + 0x7FFFu + ((v.u >> 16) & 1u);
    return (unsigned short)(r >> 16);
}
static __device__ __forceinline__ float bf2f(unsigned short b) {
    union { unsigned u; float f; } v; v.u = ((unsigned)b) << 16;
    return v.f;
}

// ---------- kernel 1: transpose x NCHW fp32 -> NHWC bf16 ----------
__global__ __launch_bounds__(256) void k_transpose(
    const float* __restrict__ x, unsigned short* __restrict__ xt)
{
    __shared__ float tile[C_][133];
    int bh = blockIdx.x;            // b*128 + h
    const float* xp = x + (size_t)(bh >> 7) * C_ * HW_ + (bh & 127) * W_;
#pragma unroll
    for (int i = 0; i < 8; ++i) {
        int idx = threadIdx.x + i * 256;     // 0..2047 float4 slots
        int c = idx >> 5, w4 = idx & 31;
        float4 v = *(const float4*)(xp + c * HW_ + w4 * 4);
        tile[c][w4*4+0] = v.x; tile[c][w4*4+1] = v.y;
        tile[c][w4*4+2] = v.z; tile[c][w4*4+3] = v.w;
    }
    __syncthreads();
    unsigned short* op = xt + (size_t)bh * (W_ * C_);
#pragma unroll
    for (int i = 0; i < 8; ++i) {
        int idx = threadIdx.x + i * 256;     // 0..2047 ushort4 slots
        int w = idx >> 4, c4 = idx & 15;
        ushort4 o;
        o.x = f2bf(tile[c4*4+0][w]); o.y = f2bf(tile[c4*4+1][w]);
        o.z = f2bf(tile[c4*4+2][w]); o.w = f2bf(tile[c4*4+3][w]);
        *(ushort4*)(op + w*64 + c4*4) = o;
    }
}

// ---------- kernel 2: pack weights into MFMA A-frag layout (bf16) ----------
// A-frag for 16x16x32: lane holds row = lane&15, k = (lane>>4)*8 + j.
// wb  : [4 otile][18 t][64 lane][8]   (o = otile*16 + lane&15, k = t*32+(lane>>4)*8+j, k = kk*64+c)
// wboff: [2 mtile][18 t][64 lane][8]  (rows >= 18 zeroed)
__global__ __launch_bounds__(256) void k_prep(
    const float* __restrict__ w_dcn, const float* __restrict__ w_off,
    unsigned short* __restrict__ wb, unsigned short* __restrict__ wboff)
{
    int i = blockIdx.x * 256 + threadIdx.x;
    if (i < O_ * 576) {
        int j = i & 7, l = (i >> 3) & 63, t = (i >> 9) % 18, ot = i / (18*512);
        int k = t*32 + ((l>>4)&3)*8 + j;
        int o = ot*16 + (l & 15);
        int kk = k >> 6, c = k & 63;
        wb[i] = f2bf(w_dcn[(o*64 + c)*9 + kk]);
    }
    int i2 = i - O_*576;
    if (i2 >= 0 && i2 < 32*576) {
        int j = i2 & 7, l = (i2 >> 3) & 63, t = (i2 >> 9) % 18, mt = i2 / (18*512);
        int k = t*32 + ((l>>4)&3)*8 + j;
        int o = mt*16 + (l & 15);
        int kk = k >> 6, c = k & 63;
        wboff[i2] = (o < OFFC_) ? f2bf(w_off[(o*64 + c)*9 + kk]) : (unsigned short)0;
    }
}

// ---------- kernel 3: offset conv via MFMA ----------
// block = (b,ho). 4 iters x 32 px. out[18 x px] = Woff[18x576] * im2col[576 x px]
__global__ __launch_bounds__(256) void k_off_mfma(
    const unsigned short* __restrict__ xt, const unsigned short* __restrict__ wboff,
    const float* __restrict__ b_off, float* __restrict__ offs)
{
    __shared__ __align__(16) char val2[2][16 * VSB];   // 36864 B
    int tid = threadIdx.x;
    int bh = blockIdx.x; int b = bh >> 7, ho = bh & 127;
    int wave = tid >> 6, lane = tid & 63;
    int mt = wave >> 1;          // M-tile this wave computes
    int rg_m = wave & 1;         // val2 region this wave computes

    bs8 afr[18];
    {
        const unsigned short* wp = wboff + ((mt*18)*64 + lane)*8;
#pragma unroll
        for (int t = 0; t < 18; ++t) afr[t] = *(const bs8*)(wp + t*512);
    }
    const unsigned short* xb = xt + (size_t)b * HW_ * 64;
    int cg = tid & 15, pp = tid >> 4;

    for (int it = 0; it < 4; ++it) {
        // fill 32 px of im2col (both regions), all 256 threads
#pragma unroll
        for (int half = 0; half < 2; ++half) {
            int pw = pp + half*16;            // 0..31
            int wo = it*32 + pw;
            int rg_f = pw >> 4, p = pw & 15;
            char* vb = &val2[rg_f][0] + p * VSB + ((cg&1)<<3);
            int ph = p & 7;
#pragma unroll
            for (int kk = 0; kk < KK_; ++kk) {
                int y = ho + kk/3 - 1;
                int xx = wo + kk%3 - 1;
                ushort4 v = make_ushort4(0,0,0,0);
                if ((unsigned)y < H_ && (unsigned)xx < W_)
                    v = *(const ushort4*)(xb + (y*W_ + xx)*64 + cg*4);
                int g8 = kk*8 + (cg>>1);
                *(ushort4*)(vb + (((g8 ^ ph) << 4))) = v;
            }
        }
        __syncthreads();
        // MFMA: wave -> (mtile mt, region rg_m)
        f32x4 acc = {0.f,0.f,0.f,0.f};
        {
            const char* vb = &val2[rg_m][0] + (lane & 15) * VSB;
            int gk = (lane >> 4) & 3;
            int ph = (lane & 15) & 7;
#pragma unroll
            for (int t = 0; t < 18; ++t) {
                bs8 bfr = *(const bs8*)(vb + (((t*4 + gk) ^ ph) << 4));
                acc = __builtin_amdgcn_mfma_f32_16x16x32_bf16(afr[t], bfr, acc, 0, 0, 0);
            }
        }
        int orow = mt*16 + ((lane>>4)&3)*4;
        int wo = it*32 + rg_m*16 + (lane & 15);
#pragma unroll
        for (int r = 0; r < 4; ++r) {
            int o = orow + r;
            if (o < OFFC_)
                offs[((b*OFFC_ + o)*H_ + ho)*W_ + wo] = acc[r] + b_off[o];
        }
        __syncthreads();
    }
}

// ---------- kernel 4: deformable conv via MFMA ----------
// block = (b,ho), full row = 8 px-tiles of 16. Weights (64x576 bf16) live in
// 72 VGPR/wave for the whole block. val tile [16px][576] bf16 in LDS, XOR-swizzled.
__global__ __launch_bounds__(256) void k_deform(
    const unsigned short* __restrict__ xt, const float* __restrict__ offs,
    const unsigned short* __restrict__ wb, const float* __restrict__ b_dcn,
    float* __restrict__ out)
{
    __shared__ __align__(16) char val[16 * VSB];        // 18432 B
    __shared__ __align__(16) float posf[8][16][KK_][4]; // 18432 B: w00,w01,w10,w11
    __shared__ __align__(16) int   posi[8][16][KK_][4]; // 18432 B: a00,a01,a10,a11
    int tid = threadIdx.x;
    int bh = blockIdx.x; int b = bh >> 7, ho = bh & 127;
    int wave = tid >> 6, lane = tid & 63;

    bs8 afr[18];
    {
        const unsigned short* wp = wb + ((wave*18)*64 + lane)*8;
#pragma unroll
        for (int t = 0; t < 18; ++t) afr[t] = *(const bs8*)(wp + t*512);
    }
    const unsigned short* xb = xt + (size_t)b * HW_ * 64;

    // ---- phase A (whole row upfront): positions/weights for 128 px x 9 taps ----
    for (int i = 0; i < 5; ++i) {
        int task = tid + i*256;
        if (task < 128*KK_) {
            int pxa = task / KK_, kk = task % KK_;   // pxa 0..127
            int wo = pxa;
            float dy = offs[((b*OFFC_ + 2*kk  )*H_ + ho)*W_ + wo];
            float dx = offs[((b*OFFC_ + 2*kk+1)*H_ + ho)*W_ + wo];
            float py = (float)(ho - 1 + kk/3) + dy;
            float px = (float)(wo - 1 + kk%3) + dx;
            float fy = floorf(py), fx = floorf(px);
            int y0 = (int)fy, x0 = (int)fx;
            float ly = py - fy, lx = px - fx;
            int y1 = y0 + 1, x1 = x0 + 1;
            float my0 = ((unsigned)y0 < H_) ? 1.f : 0.f;
            float my1 = ((unsigned)y1 < H_) ? 1.f : 0.f;
            float mx0 = ((unsigned)x0 < W_) ? 1.f : 0.f;
            float mx1 = ((unsigned)x1 < W_) ? 1.f : 0.f;
            int y0c = min(max(y0,0),H_-1), y1c = min(max(y1,0),H_-1);
            int x0c = min(max(x0,0),W_-1), x1c = min(max(x1,0),W_-1);
            int t8 = pxa >> 4, p = pxa & 15;
            posf[t8][p][kk][0] = (1.f-ly)*(1.f-lx)*my0*mx0;
            posf[t8][p][kk][1] = (1.f-ly)*lx*my0*mx1;
            posf[t8][p][kk][2] = ly*(1.f-lx)*my1*mx0;
            posf[t8][p][kk][3] = ly*lx*my1*mx1;
            posi[t8][p][kk][0] = (y0c*W_ + x0c)*64;
            posi[t8][p][kk][1] = (y0c*W_ + x1c)*64;
            posi[t8][p][kk][2] = (y1c*W_ + x0c)*64;
            posi[t8][p][kk][3] = (y1c*W_ + x1c)*64;
        }
    }
    __syncthreads();

    int cg = tid & 15, p_b = tid >> 4;    // phase B roles (cg fastest -> coalesced)
    for (int tp = 0; tp < 8; ++tp) {
        // ---- phase B: bilinear gather -> val[p][k] bf16, swizzled ----
        {
            char* vb = val + p_b * VSB + ((cg&1)<<3);
            int ph = p_b & 7;
            for (int kk = 0; kk < KK_; ++kk) {
                float4 wv = *(const float4*)posf[tp][p_b][kk];
                int4   av = *(const int4*)posi[tp][p_b][kk];
                const unsigned short* s0 = xb + av.x + cg*4;
                const unsigned short* s1 = xb + av.y + cg*4;
                const unsigned short* s2 = xb + av.z + cg*4;
                const unsigned short* s3 = xb + av.w + cg*4;
                ushort4 c0 = *(const ushort4*)s0;
                ushort4 c1 = *(const ushort4*)s1;
                ushort4 c2 = *(const ushort4*)s2;
                ushort4 c3 = *(const ushort4*)s3;
                float v0 = wv.x*bf2f(c0.x) + wv.y*bf2f(c1.x) + wv.z*bf2f(c2.x) + wv.w*bf2f(c3.x);
                float v1 = wv.x*bf2f(c0.y) + wv.y*bf2f(c1.y) + wv.z*bf2f(c2.y) + wv.w*bf2f(c3.y);
                float v2 = wv.x*bf2f(c0.z) + wv.y*bf2f(c1.z) + wv.z*bf2f(c2.z) + wv.w*bf2f(c3.z);
                float v3 = wv.x*bf2f(c0.w) + wv.y*bf2f(c1.w) + wv.z*bf2f(c2.w) + wv.w*bf2f(c3.w);
                ushort4 ov;
                ov.x = f2bf(v0); ov.y = f2bf(v1); ov.z = f2bf(v2); ov.w = f2bf(v3);
                int g8 = kk*8 + (cg>>1);
                *(ushort4*)(vb + ((g8 ^ ph) << 4)) = ov;
            }
        }
        __syncthreads();
        // ---- phase C: 18 MFMA, each wave owns 16 output channels ----
        {
            f32x4 acc = {0.f,0.f,0.f,0.f};
            const char* vb = val + (lane & 15) * VSB;
            int gk = (lane >> 4) & 3;
            int ph = (lane & 15) & 7;
#pragma unroll
            for (int t = 0; t < 18; ++t) {
                bs8 bfr = *(const bs8*)(vb + (((t*4 + gk) ^ ph) << 4));
                acc = __builtin_amdgcn_mfma_f32_16x16x32_bf16(afr[t], bfr, acc, 0, 0, 0);
            }
            int orow = wave*16 + ((lane>>4)&3)*4;
            int wo = tp*16 + (lane & 15);
#pragma unroll
            for (int r = 0; r < 4; ++r) {
                int o = orow + r;
                out[((b*O_ + o)*H_ + ho)*W_ + wo] = acc[r] + b_dcn[o];
            }
        }
        __syncthreads();
    }
}

extern "C" void kernel_launch(void* const* d_in, const int* in_sizes, int n_in,
                              void* d_out, int out_size, void* d_ws, size_t ws_size,
                              hipStream_t stream) {
    const float* x     = (const float*)d_in[0];
    const float* w_off = (const float*)d_in[1];
    const float* b_off = (const float*)d_in[2];
    const float* w_dcn = (const float*)d_in[3];
    const float* b_dcn = (const float*)d_in[4];
    float* out = (float*)d_out;

    char* ws = (char*)d_ws;
    unsigned short* xt   = (unsigned short*)ws;                    // 8,388,608 B
    float*          offs = (float*)(ws + 8388608);                 // 4,718,592 B
    unsigned short* wb   = (unsigned short*)(ws + 8388608 + 4718592);   // 73,728 B
    unsigned short* wboff = wb + O_*576;                           // 36,864 B

    k_transpose<<<B_ * H_, 256, 0, stream>>>(x, xt);
    k_prep<<<216, 256, 0, stream>>>(w_dcn, w_off, wb, wboff);
    k_off_mfma<<<B_ * H_, 256, 0, stream>>>(xt, wboff, b_off, offs);
    k_deform<<<B_ * H_, 256, 0, stream>>>(xt, offs, wb, b_dcn, out);
}

// Round 3
// 56.754 us; speedup vs baseline: 8.1365x; 1.6056x over previous
//
#include <hip/hip_runtime.h>

#define B_ 4
#define C_ 64
#define H_ 128
#define W_ 128
#define O_ 64
#define KK_ 9
#define OFFC_ 18
#define HW_ (H_*W_)
#define VSB 1152   // val row stride in bytes (576 bf16)

typedef __attribute__((ext_vector_type(8))) short bs8;
typedef __attribute__((ext_vector_type(8))) unsigned short us8;
typedef __attribute__((ext_vector_type(4))) float f32x4;

static __device__ __forceinline__ unsigned short f2bf(float f) {
    union { float f; unsigned u; } v; v.f = f;
    unsigned r = v.u + 0x7FFFu + ((v.u >> 16) & 1u);
    return (unsigned short)(r >> 16);
}
static __device__ __forceinline__ float bf2f(unsigned short b) {
    union { unsigned u; float f; } v; v.u = ((unsigned)b) << 16;
    return v.f;
}

// ---------- kernel 1: transpose x NCHW fp32 -> NHWC bf16 ----------
__global__ __launch_bounds__(256) void k_transpose(
    const float* __restrict__ x, unsigned short* __restrict__ xt)
{
    __shared__ float tile[C_][133];
    int bh = blockIdx.x;            // b*128 + h
    const float* xp = x + (size_t)(bh >> 7) * C_ * HW_ + (bh & 127) * W_;
#pragma unroll
    for (int i = 0; i < 8; ++i) {
        int idx = threadIdx.x + i * 256;     // 0..2047 float4 slots
        int c = idx >> 5, w4 = idx & 31;
        float4 v = *(const float4*)(xp + c * HW_ + w4 * 4);
        tile[c][w4*4+0] = v.x; tile[c][w4*4+1] = v.y;
        tile[c][w4*4+2] = v.z; tile[c][w4*4+3] = v.w;
    }
    __syncthreads();
    unsigned short* op = xt + (size_t)bh * (W_ * C_);
#pragma unroll
    for (int i = 0; i < 8; ++i) {
        int idx = threadIdx.x + i * 256;     // 0..2047 ushort4 slots
        int w = idx >> 4, c4 = idx & 15;
        ushort4 o;
        o.x = f2bf(tile[c4*4+0][w]); o.y = f2bf(tile[c4*4+1][w]);
        o.z = f2bf(tile[c4*4+2][w]); o.w = f2bf(tile[c4*4+3][w]);
        *(ushort4*)(op + w*64 + c4*4) = o;
    }
}

// ---------- kernel 2: pack weights into MFMA A-frag layout (bf16) ----------
__global__ __launch_bounds__(256) void k_prep(
    const float* __restrict__ w_dcn, const float* __restrict__ w_off,
    unsigned short* __restrict__ wb, unsigned short* __restrict__ wboff)
{
    int i = blockIdx.x * 256 + threadIdx.x;
    if (i < O_ * 576) {
        int j = i & 7, l = (i >> 3) & 63, t = (i >> 9) % 18, ot = i / (18*512);
        int k = t*32 + ((l>>4)&3)*8 + j;
        int o = ot*16 + (l & 15);
        int kk = k >> 6, c = k & 63;
        wb[i] = f2bf(w_dcn[(o*64 + c)*9 + kk]);
    }
    int i2 = i - O_*576;
    if (i2 >= 0 && i2 < 32*576) {
        int j = i2 & 7, l = (i2 >> 3) & 63, t = (i2 >> 9) % 18, mt = i2 / (18*512);
        int k = t*32 + ((l>>4)&3)*8 + j;
        int o = mt*16 + (l & 15);
        int kk = k >> 6, c = k & 63;
        wboff[i2] = (o < OFFC_) ? f2bf(w_off[(o*64 + c)*9 + kk]) : (unsigned short)0;
    }
}

// ---------- kernel 3: offset conv via MFMA ----------
// block = 32 px of one row; grid = B*H*4 = 2048.
__global__ __launch_bounds__(256) void k_off_mfma(
    const unsigned short* __restrict__ xt, const unsigned short* __restrict__ wboff,
    const float* __restrict__ b_off, float* __restrict__ offs)
{
    __shared__ __align__(16) char val2[2][16 * VSB];   // 36864 B
    int tid = threadIdx.x;
    int blk = blockIdx.x;
    int wt2 = blk & 3, ho = (blk >> 2) & 127, b = blk >> 9;
    int wo0 = wt2 * 32;
    int wave = tid >> 6, lane = tid & 63;
    int mt = wave >> 1;          // M-tile (0: rows 0-15, 1: rows 16-17)
    int rg_m = wave & 1;         // px region

    bs8 afr[18];
    {
        const unsigned short* wp = wboff + ((mt*18)*64 + lane)*8;
#pragma unroll
        for (int t = 0; t < 18; ++t) afr[t] = *(const bs8*)(wp + t*512);
    }

    // ---- im2col gather: thread = (px32 = tid>>3, cg8 = tid&7), 8 ch per load ----
    {
        int cg8 = tid & 7, px32 = tid >> 3;
        int rg_f = px32 >> 4, p = px32 & 15, ph = p & 7;
        char* vb = &val2[rg_f][0] + p * VSB;
        const char* xbc = (const char*)xt + (size_t)b * HW_ * 128;
        int wo = wo0 + px32;
#pragma unroll
        for (int kk = 0; kk < KK_; ++kk) {
            int y = ho + kk/3 - 1;
            int xx = wo + kk%3 - 1;
            us8 v = {0,0,0,0,0,0,0,0};
            if ((unsigned)y < H_ && (unsigned)xx < W_)
                v = *(const us8*)(xbc + (y*W_ + xx)*128 + cg8*16);
            int g8 = kk*8 + cg8;
            *(us8*)(vb + ((g8 ^ ph) << 4)) = v;
        }
    }
    __syncthreads();

    // ---- MFMA ----
    f32x4 acc = {0.f,0.f,0.f,0.f};
    {
        const char* vb = &val2[rg_m][0] + (lane & 15) * VSB;
        int gk = (lane >> 4) & 3;
        int ph = (lane & 15) & 7;
#pragma unroll
        for (int t = 0; t < 18; ++t) {
            bs8 bfr = *(const bs8*)(vb + (((t*4 + gk) ^ ph) << 4));
            acc = __builtin_amdgcn_mfma_f32_16x16x32_bf16(afr[t], bfr, acc, 0, 0, 0);
        }
    }
    int orow = mt*16 + ((lane>>4)&3)*4;
    int wo = wo0 + rg_m*16 + (lane & 15);
#pragma unroll
    for (int r = 0; r < 4; ++r) {
        int o = orow + r;
        if (o < OFFC_)
            offs[((b*OFFC_ + o)*H_ + ho)*W_ + wo] = acc[r] + b_off[o];
    }
}

// ---------- kernel 4: deformable conv via MFMA ----------
// block = 16 px of one row; grid = B*H*8 = 4096. Weights: wave w holds M-tile w
// A-frag in 72 VGPRs. val [16px][576] bf16 LDS, 16B-granule XOR swizzle.
__global__ __launch_bounds__(256) void k_deform(
    const unsigned short* __restrict__ xt, const float* __restrict__ offs,
    const unsigned short* __restrict__ wb, const float* __restrict__ b_dcn,
    float* __restrict__ out)
{
    __shared__ __align__(16) char val[16 * VSB];        // 18432 B
    __shared__ __align__(16) float posf[16][KK_][4];    // 2304 B: w00,w01,w10,w11
    __shared__ __align__(16) int   posi[16][KK_][4];    // 2304 B: byte offsets
    int tid = threadIdx.x;
    int blk = blockIdx.x;
    int wt = blk & 7, ho = (blk >> 3) & 127, b = blk >> 10;
    int wo0 = wt * 16;
    int wave = tid >> 6, lane = tid & 63;

    bs8 afr[18];
    {
        const unsigned short* wp = wb + ((wave*18)*64 + lane)*8;
#pragma unroll
        for (int t = 0; t < 18; ++t) afr[t] = *(const bs8*)(wp + t*512);
    }

    // ---- phase A: positions/weights for 16 px x 9 taps (144 tasks) ----
    if (tid < 16*KK_) {
        int p = tid / KK_, kk = tid % KK_;
        int wo = wo0 + p;
        float dy = offs[((b*OFFC_ + 2*kk  )*H_ + ho)*W_ + wo];
        float dx = offs[((b*OFFC_ + 2*kk+1)*H_ + ho)*W_ + wo];
        float py = (float)(ho - 1 + kk/3) + dy;
        float px = (float)(wo - 1 + kk%3) + dx;
        float fy = floorf(py), fx = floorf(px);
        int y0 = (int)fy, x0 = (int)fx;
        float ly = py - fy, lx = px - fx;
        int y1 = y0 + 1, x1 = x0 + 1;
        float my0 = ((unsigned)y0 < H_) ? 1.f : 0.f;
        float my1 = ((unsigned)y1 < H_) ? 1.f : 0.f;
        float mx0 = ((unsigned)x0 < W_) ? 1.f : 0.f;
        float mx1 = ((unsigned)x1 < W_) ? 1.f : 0.f;
        int y0c = min(max(y0,0),H_-1), y1c = min(max(y1,0),H_-1);
        int x0c = min(max(x0,0),W_-1), x1c = min(max(x1,0),W_-1);
        posf[p][kk][0] = (1.f-ly)*(1.f-lx)*my0*mx0;
        posf[p][kk][1] = (1.f-ly)*lx*my0*mx1;
        posf[p][kk][2] = ly*(1.f-lx)*my1*mx0;
        posf[p][kk][3] = ly*lx*my1*mx1;
        posi[p][kk][0] = (y0c*W_ + x0c)*128;    // byte offsets into NHWC bf16
        posi[p][kk][1] = (y0c*W_ + x1c)*128;
        posi[p][kk][2] = (y1c*W_ + x0c)*128;
        posi[p][kk][3] = (y1c*W_ + x1c)*128;
    }
    __syncthreads();

    // ---- phase B: bilinear gather, 8 ch (16 B) per thread-task ----
    // thread = (kh = tid>>7, p = (tid>>3)&15, cg8 = tid&7); kk = 2*i + kh
    {
        int cg8 = tid & 7, p = (tid >> 3) & 15, kh = tid >> 7;
        int ph = p & 7;
        char* vb = val + p * VSB;
        const char* xbc = (const char*)xt + (size_t)b * HW_ * 128;
        int nkk = kh ? 4 : 5;
#pragma unroll 5
        for (int i = 0; i < nkk; ++i) {
            int kk = 2*i + kh;
            float4 wv = *(const float4*)posf[p][kk];
            int4   av = *(const int4*)posi[p][kk];
            us8 c0 = *(const us8*)(xbc + av.x + cg8*16);
            us8 c1 = *(const us8*)(xbc + av.y + cg8*16);
            us8 c2 = *(const us8*)(xbc + av.z + cg8*16);
            us8 c3 = *(const us8*)(xbc + av.w + cg8*16);
            us8 ov;
#pragma unroll
            for (int j = 0; j < 8; ++j) {
                float v = wv.x*bf2f(c0[j]) + wv.y*bf2f(c1[j])
                        + wv.z*bf2f(c2[j]) + wv.w*bf2f(c3[j]);
                ov[j] = f2bf(v);
            }
            int g8 = kk*8 + cg8;
            *(us8*)(vb + ((g8 ^ ph) << 4)) = ov;
        }
    }
    __syncthreads();

    // ---- phase C: 18 MFMA, wave w owns output channels w*16..w*16+15 ----
    {
        f32x4 acc = {0.f,0.f,0.f,0.f};
        const char* vb = val + (lane & 15) * VSB;
        int gk = (lane >> 4) & 3;
        int ph = (lane & 15) & 7;
#pragma unroll
        for (int t = 0; t < 18; ++t) {
            bs8 bfr = *(const bs8*)(vb + (((t*4 + gk) ^ ph) << 4));
            acc = __builtin_amdgcn_mfma_f32_16x16x32_bf16(afr[t], bfr, acc, 0, 0, 0);
        }
        int orow = wave*16 + ((lane>>4)&3)*4;
        int wo = wo0 + (lane & 15);
#pragma unroll
        for (int r = 0; r < 4; ++r) {
            int o = orow + r;
            out[((b*O_ + o)*H_ + ho)*W_ + wo] = acc[r] + b_dcn[o];
        }
    }
}

extern "C" void kernel_launch(void* const* d_in, const int* in_sizes, int n_in,
                              void* d_out, int out_size, void* d_ws, size_t ws_size,
                              hipStream_t stream) {
    const float* x     = (const float*)d_in[0];
    const float* w_off = (const float*)d_in[1];
    const float* b_off = (const float*)d_in[2];
    const float* w_dcn = (const float*)d_in[3];
    const float* b_dcn = (const float*)d_in[4];
    float* out = (float*)d_out;

    char* ws = (char*)d_ws;
    unsigned short* xt   = (unsigned short*)ws;                    // 8,388,608 B
    float*          offs = (float*)(ws + 8388608);                 // 4,718,592 B
    unsigned short* wb   = (unsigned short*)(ws + 8388608 + 4718592);   // 73,728 B
    unsigned short* wboff = wb + O_*576;                           // 36,864 B

    k_transpose<<<B_ * H_, 256, 0, stream>>>(x, xt);
    k_prep<<<216, 256, 0, stream>>>(w_dcn, w_off, wb, wboff);
    k_off_mfma<<<B_ * H_ * 4, 256, 0, stream>>>(xt, wboff, b_off, offs);
    k_deform<<<B_ * H_ * 8, 256, 0, stream>>>(xt, offs, wb, b_dcn, out);
}

// Round 4
// 53.195 us; speedup vs baseline: 8.6809x; 1.0669x over previous
//
#include <hip/hip_runtime.h>

#define B_ 4
#define C_ 64
#define H_ 128
#define W_ 128
#define O_ 64
#define KK_ 9
#define OFFC_ 18
#define HW_ (H_*W_)
#define VSB 1152   // val row stride in bytes (576 fp16)

typedef __attribute__((ext_vector_type(8))) _Float16 h8;
typedef __attribute__((ext_vector_type(4))) _Float16 h4;
typedef __attribute__((ext_vector_type(4))) float f32x4;

// ---------- kernel 1: transpose x NCHW fp32 -> NHWC fp16, + weight prep ----------
// blocks 0..511: transpose one (b,h) row. blocks 512..727: pack weights.
__global__ __launch_bounds__(256) void k_pre(
    const float* __restrict__ x, const float* __restrict__ w_dcn,
    const float* __restrict__ w_off, _Float16* __restrict__ xt,
    _Float16* __restrict__ wb, _Float16* __restrict__ wboff)
{
    __shared__ float tile[C_][133];
    int blk = blockIdx.x;
    if (blk < 512) {
        const float* xp = x + (size_t)(blk >> 7) * C_ * HW_ + (blk & 127) * W_;
#pragma unroll
        for (int i = 0; i < 8; ++i) {
            int idx = threadIdx.x + i * 256;     // 0..2047 float4 slots
            int c = idx >> 5, w4 = idx & 31;
            float4 v = *(const float4*)(xp + c * HW_ + w4 * 4);
            tile[c][w4*4+0] = v.x; tile[c][w4*4+1] = v.y;
            tile[c][w4*4+2] = v.z; tile[c][w4*4+3] = v.w;
        }
        __syncthreads();
        _Float16* op = xt + (size_t)blk * (W_ * C_);
#pragma unroll
        for (int i = 0; i < 8; ++i) {
            int idx = threadIdx.x + i * 256;     // 0..2047 h4 slots
            int w = idx >> 4, c4 = idx & 15;
            h4 o;
            o.x = (_Float16)tile[c4*4+0][w]; o.y = (_Float16)tile[c4*4+1][w];
            o.z = (_Float16)tile[c4*4+2][w]; o.w = (_Float16)tile[c4*4+3][w];
            *(h4*)(op + w*64 + c4*4) = o;
        }
    } else {
        int i = (blk - 512) * 256 + threadIdx.x;
        if (i < O_ * 576) {
            int j = i & 7, l = (i >> 3) & 63, t = (i >> 9) % 18, ot = i / (18*512);
            int k = t*32 + ((l>>4)&3)*8 + j;
            int o = ot*16 + (l & 15);
            int kk = k >> 6, c = k & 63;
            wb[i] = (_Float16)w_dcn[(o*64 + c)*9 + kk];
        }
        int i2 = i - O_*576;
        if (i2 >= 0 && i2 < 32*576) {
            int j = i2 & 7, l = (i2 >> 3) & 63, t = (i2 >> 9) % 18, mt = i2 / (18*512);
            int k = t*32 + ((l>>4)&3)*8 + j;
            int o = mt*16 + (l & 15);
            int kk = k >> 6, c = k & 63;
            wboff[i2] = (o < OFFC_) ? (_Float16)w_off[(o*64 + c)*9 + kk] : (_Float16)0.f;
        }
    }
}

// ---------- kernel 2: offset conv via MFMA ----------
// block = 32 px of one row; grid = B*H*4 = 2048.
__global__ __launch_bounds__(256) void k_off_mfma(
    const _Float16* __restrict__ xt, const _Float16* __restrict__ wboff,
    const float* __restrict__ b_off, float* __restrict__ offs)
{
    __shared__ __align__(16) char val2[2][16 * VSB];   // 36864 B
    int tid = threadIdx.x;
    int blk = blockIdx.x;
    int wt2 = blk & 3, ho = (blk >> 2) & 127, b = blk >> 9;
    int wo0 = wt2 * 32;
    int wave = tid >> 6, lane = tid & 63;
    int mt = wave >> 1;          // M-tile (0: rows 0-15, 1: rows 16-17)
    int rg_m = wave & 1;         // px region

    h8 afr[18];
    {
        const _Float16* wp = wboff + ((mt*18)*64 + lane)*8;
#pragma unroll
        for (int t = 0; t < 18; ++t) afr[t] = *(const h8*)(wp + t*512);
    }

    // ---- im2col gather: thread = (px32 = tid>>3, cg8 = tid&7), 8 ch per load ----
    {
        int cg8 = tid & 7, px32 = tid >> 3;
        int rg_f = px32 >> 4, p = px32 & 15, ph = p & 7;
        char* vb = &val2[rg_f][0] + p * VSB;
        const char* xbc = (const char*)xt + (size_t)b * HW_ * 128;
        int wo = wo0 + px32;
#pragma unroll
        for (int kk = 0; kk < KK_; ++kk) {
            int y = ho + kk/3 - 1;
            int xx = wo + kk%3 - 1;
            h8 v = {0,0,0,0,0,0,0,0};
            if ((unsigned)y < H_ && (unsigned)xx < W_)
                v = *(const h8*)(xbc + (y*W_ + xx)*128 + cg8*16);
            int g8 = kk*8 + cg8;
            *(h8*)(vb + ((g8 ^ ph) << 4)) = v;
        }
    }
    __syncthreads();

    // ---- MFMA ----
    f32x4 acc = {0.f,0.f,0.f,0.f};
    {
        const char* vb = &val2[rg_m][0] + (lane & 15) * VSB;
        int gk = (lane >> 4) & 3;
        int ph = (lane & 15) & 7;
#pragma unroll
        for (int t = 0; t < 18; ++t) {
            h8 bfr = *(const h8*)(vb + (((t*4 + gk) ^ ph) << 4));
            acc = __builtin_amdgcn_mfma_f32_16x16x32_f16(afr[t], bfr, acc, 0, 0, 0);
        }
    }
    int orow = mt*16 + ((lane>>4)&3)*4;
    int wo = wo0 + rg_m*16 + (lane & 15);
#pragma unroll
    for (int r = 0; r < 4; ++r) {
        int o = orow + r;
        if (o < OFFC_)
            offs[((b*OFFC_ + o)*H_ + ho)*W_ + wo] = acc[r] + b_off[o];
    }
}

// ---------- kernel 3: deformable conv via MFMA ----------
// block = 16 px of one row; grid = B*H*8 = 4096. Wave w holds M-tile w A-frag
// in 72 VGPRs. val [16px][576] fp16 LDS, 16B-granule XOR swizzle.
__global__ __launch_bounds__(256) void k_deform(
    const _Float16* __restrict__ xt, const float* __restrict__ offs,
    const _Float16* __restrict__ wb, const float* __restrict__ b_dcn,
    float* __restrict__ out)
{
    __shared__ __align__(16) char val[16 * VSB];        // 18432 B
    __shared__ __align__(16) float posf[16][KK_][4];    // 2304 B: w00,w01,w10,w11
    __shared__ __align__(16) int   posi[16][KK_][4];    // 2304 B: byte offsets
    int tid = threadIdx.x;
    int blk = blockIdx.x;
    int wt = blk & 7, ho = (blk >> 3) & 127, b = blk >> 10;
    int wo0 = wt * 16;
    int wave = tid >> 6, lane = tid & 63;

    h8 afr[18];
    {
        const _Float16* wp = wb + ((wave*18)*64 + lane)*8;
#pragma unroll
        for (int t = 0; t < 18; ++t) afr[t] = *(const h8*)(wp + t*512);
    }

    // ---- phase A: positions/weights for 16 px x 9 taps (144 tasks) ----
    if (tid < 16*KK_) {
        int p = tid / KK_, kk = tid % KK_;
        int wo = wo0 + p;
        float dy = offs[((b*OFFC_ + 2*kk  )*H_ + ho)*W_ + wo];
        float dx = offs[((b*OFFC_ + 2*kk+1)*H_ + ho)*W_ + wo];
        float py = (float)(ho - 1 + kk/3) + dy;
        float px = (float)(wo - 1 + kk%3) + dx;
        float fy = floorf(py), fx = floorf(px);
        int y0 = (int)fy, x0 = (int)fx;
        float ly = py - fy, lx = px - fx;
        int y1 = y0 + 1, x1 = x0 + 1;
        float my0 = ((unsigned)y0 < H_) ? 1.f : 0.f;
        float my1 = ((unsigned)y1 < H_) ? 1.f : 0.f;
        float mx0 = ((unsigned)x0 < W_) ? 1.f : 0.f;
        float mx1 = ((unsigned)x1 < W_) ? 1.f : 0.f;
        int y0c = min(max(y0,0),H_-1), y1c = min(max(y1,0),H_-1);
        int x0c = min(max(x0,0),W_-1), x1c = min(max(x1,0),W_-1);
        posf[p][kk][0] = (1.f-ly)*(1.f-lx)*my0*mx0;
        posf[p][kk][1] = (1.f-ly)*lx*my0*mx1;
        posf[p][kk][2] = ly*(1.f-lx)*my1*mx0;
        posf[p][kk][3] = ly*lx*my1*mx1;
        posi[p][kk][0] = (y0c*W_ + x0c)*128;    // byte offsets into NHWC fp16
        posi[p][kk][1] = (y0c*W_ + x1c)*128;
        posi[p][kk][2] = (y1c*W_ + x0c)*128;
        posi[p][kk][3] = (y1c*W_ + x1c)*128;
    }
    __syncthreads();

    // ---- phase B: bilinear gather, 8 ch (16 B) per task, packed fp16 blend ----
    {
        int cg8 = tid & 7, p = (tid >> 3) & 15, kh = tid >> 7;
        int ph = p & 7;
        char* vb = val + p * VSB;
        const char* xbc = (const char*)xt + (size_t)b * HW_ * 128;
        int nkk = kh ? 4 : 5;
#pragma unroll 5
        for (int i = 0; i < nkk; ++i) {
            int kk = 2*i + kh;
            float4 wv = *(const float4*)posf[p][kk];
            int4   av = *(const int4*)posi[p][kk];
            h8 c0 = *(const h8*)(xbc + av.x + cg8*16);
            h8 c1 = *(const h8*)(xbc + av.y + cg8*16);
            h8 c2 = *(const h8*)(xbc + av.z + cg8*16);
            h8 c3 = *(const h8*)(xbc + av.w + cg8*16);
            _Float16 h00 = (_Float16)wv.x, h01 = (_Float16)wv.y;
            _Float16 h10 = (_Float16)wv.z, h11 = (_Float16)wv.w;
            h8 w00v = {h00,h00,h00,h00,h00,h00,h00,h00};
            h8 w01v = {h01,h01,h01,h01,h01,h01,h01,h01};
            h8 w10v = {h10,h10,h10,h10,h10,h10,h10,h10};
            h8 w11v = {h11,h11,h11,h11,h11,h11,h11,h11};
            h8 r = c0*w00v + c1*w01v + c2*w10v + c3*w11v;
            int g8 = kk*8 + cg8;
            *(h8*)(vb + ((g8 ^ ph) << 4)) = r;
        }
    }
    __syncthreads();

    // ---- phase C: 18 MFMA, wave w owns output channels w*16..w*16+15 ----
    {
        f32x4 acc = {0.f,0.f,0.f,0.f};
        const char* vb = val + (lane & 15) * VSB;
        int gk = (lane >> 4) & 3;
        int ph = (lane & 15) & 7;
#pragma unroll
        for (int t = 0; t < 18; ++t) {
            h8 bfr = *(const h8*)(vb + (((t*4 + gk) ^ ph) << 4));
            acc = __builtin_amdgcn_mfma_f32_16x16x32_f16(afr[t], bfr, acc, 0, 0, 0);
        }
        int orow = wave*16 + ((lane>>4)&3)*4;
        int wo = wo0 + (lane & 15);
#pragma unroll
        for (int r = 0; r < 4; ++r) {
            int o = orow + r;
            out[((b*O_ + o)*H_ + ho)*W_ + wo] = acc[r] + b_dcn[o];
        }
    }
}

extern "C" void kernel_launch(void* const* d_in, const int* in_sizes, int n_in,
                              void* d_out, int out_size, void* d_ws, size_t ws_size,
                              hipStream_t stream) {
    const float* x     = (const float*)d_in[0];
    const float* w_off = (const float*)d_in[1];
    const float* b_off = (const float*)d_in[2];
    const float* w_dcn = (const float*)d_in[3];
    const float* b_dcn = (const float*)d_in[4];
    float* out = (float*)d_out;

    char* ws = (char*)d_ws;
    _Float16* xt   = (_Float16*)ws;                          // 8,388,608 B
    float*    offs = (float*)(ws + 8388608);                 // 4,718,592 B
    _Float16* wb   = (_Float16*)(ws + 8388608 + 4718592);    // 73,728 B
    _Float16* wboff = wb + O_*576;                           // 36,864 B

    k_pre<<<728, 256, 0, stream>>>(x, w_dcn, w_off, xt, wb, wboff);
    k_off_mfma<<<B_ * H_ * 4, 256, 0, stream>>>(xt, wboff, b_off, offs);
    k_deform<<<B_ * H_ * 8, 256, 0, stream>>>(xt, offs, wb, b_dcn, out);
}

// Round 5
// 46.308 us; speedup vs baseline: 9.9718x; 1.1487x over previous
//
#include <hip/hip_runtime.h>

#define B_ 4
#define C_ 64
#define H_ 128
#define W_ 128
#define O_ 64
#define KK_ 9
#define OFFC_ 18
#define HW_ (H_*W_)
#define VSB 1152   // val row stride in bytes (576 fp16)

typedef __attribute__((ext_vector_type(8))) _Float16 h8;
typedef __attribute__((ext_vector_type(4))) _Float16 h4;
typedef __attribute__((ext_vector_type(4))) float f32x4;

// ---------- kernel 1: transpose x NCHW fp32 -> NHWC fp16, + weight prep ----------
// blocks 0..511: transpose one (b,h) row. blocks 512..727: pack weights.
__global__ __launch_bounds__(256) void k_pre(
    const float* __restrict__ x, const float* __restrict__ w_dcn,
    const float* __restrict__ w_off, _Float16* __restrict__ xt,
    _Float16* __restrict__ wb, _Float16* __restrict__ wboff)
{
    __shared__ float tile[C_][133];
    int blk = blockIdx.x;
    if (blk < 512) {
        const float* xp = x + (size_t)(blk >> 7) * C_ * HW_ + (blk & 127) * W_;
#pragma unroll
        for (int i = 0; i < 8; ++i) {
            int idx = threadIdx.x + i * 256;     // 0..2047 float4 slots
            int c = idx >> 5, w4 = idx & 31;
            float4 v = *(const float4*)(xp + c * HW_ + w4 * 4);
            tile[c][w4*4+0] = v.x; tile[c][w4*4+1] = v.y;
            tile[c][w4*4+2] = v.z; tile[c][w4*4+3] = v.w;
        }
        __syncthreads();
        _Float16* op = xt + (size_t)blk * (W_ * C_);
#pragma unroll
        for (int i = 0; i < 8; ++i) {
            int idx = threadIdx.x + i * 256;     // 0..2047 h4 slots
            int w = idx >> 4, c4 = idx & 15;
            h4 o;
            o.x = (_Float16)tile[c4*4+0][w]; o.y = (_Float16)tile[c4*4+1][w];
            o.z = (_Float16)tile[c4*4+2][w]; o.w = (_Float16)tile[c4*4+3][w];
            *(h4*)(op + w*64 + c4*4) = o;
        }
    } else {
        int i = (blk - 512) * 256 + threadIdx.x;
        if (i < O_ * 576) {
            int j = i & 7, l = (i >> 3) & 63, t = (i >> 9) % 18, ot = i / (18*512);
            int k = t*32 + ((l>>4)&3)*8 + j;
            int o = ot*16 + (l & 15);
            int kk = k >> 6, c = k & 63;
            wb[i] = (_Float16)w_dcn[(o*64 + c)*9 + kk];
        }
        int i2 = i - O_*576;
        if (i2 >= 0 && i2 < 32*576) {
            int j = i2 & 7, l = (i2 >> 3) & 63, t = (i2 >> 9) % 18, mt = i2 / (18*512);
            int k = t*32 + ((l>>4)&3)*8 + j;
            int o = mt*16 + (l & 15);
            int kk = k >> 6, c = k & 63;
            wboff[i2] = (o < OFFC_) ? (_Float16)w_off[(o*64 + c)*9 + kk] : (_Float16)0.f;
        }
    }
}

// ---------- kernel 2: fused offset-conv + deformable conv ----------
// block = 16 px of one row; grid = B*H*8 = 4096, XCD-swizzled so each XCD
// owns 64 consecutive rows of one batch (xt slice ~1.06 MB -> L2-resident).
__global__ __launch_bounds__(256) void k_fused(
    const _Float16* __restrict__ xt, const _Float16* __restrict__ wb,
    const _Float16* __restrict__ wboff, const float* __restrict__ b_off,
    const float* __restrict__ b_dcn, float* __restrict__ out)
{
    __shared__ __align__(16) char val[16 * VSB];        // 18432 B
    __shared__ __align__(16) float offl[OFFC_][16];     // 1152 B
    __shared__ __align__(16) float posf[16][KK_][4];    // 2304 B
    __shared__ __align__(16) int   posi[16][KK_][4];    // 2304 B

    int tid = threadIdx.x;
    int d = blockIdx.x;
    int blk = (d & 7) * 512 + (d >> 3);   // XCD-contiguous chunks
    int wt = blk & 7, ho = (blk >> 3) & 127, b = blk >> 10;
    int wo0 = wt * 16;
    int wave = tid >> 6, lane = tid & 63;
    const char* xbc = (const char*)xt + (size_t)b * HW_ * 128;

    // ---- phase 0: regular im2col gather for offset conv -> val ----
    {
        int cg8 = tid & 7, p = (tid >> 3) & 15, kh = tid >> 7;
        int ph = p & 7;
        char* vb = val + p * VSB;
        int nkk = kh ? 4 : 5;
#pragma unroll 5
        for (int i = 0; i < nkk; ++i) {
            int kk = 2*i + kh;
            int y = ho + kk/3 - 1;
            int xx = wo0 + p + kk%3 - 1;
            h8 v = {0,0,0,0,0,0,0,0};
            if ((unsigned)y < H_ && (unsigned)xx < W_)
                v = *(const h8*)(xbc + (y*W_ + xx)*128 + cg8*16);
            int g8 = kk*8 + cg8;
            *(h8*)(vb + ((g8 ^ ph) << 4)) = v;
        }
    }
    __syncthreads();

    // ---- phase 1: offset MFMA (waves 0-1), offsets -> offl ----
    if (wave < 2) {
        h8 afr[18];
        const _Float16* wp = wboff + ((wave*18)*64 + lane)*8;
#pragma unroll
        for (int t = 0; t < 18; ++t) afr[t] = *(const h8*)(wp + t*512);
        f32x4 acc = {0.f,0.f,0.f,0.f};
        const char* vb = val + (lane & 15) * VSB;
        int gk = (lane >> 4) & 3;
        int ph = (lane & 15) & 7;
#pragma unroll
        for (int t = 0; t < 18; ++t) {
            h8 bfr = *(const h8*)(vb + (((t*4 + gk) ^ ph) << 4));
            acc = __builtin_amdgcn_mfma_f32_16x16x32_f16(afr[t], bfr, acc, 0, 0, 0);
        }
        int orow = wave*16 + gk*4;
#pragma unroll
        for (int r = 0; r < 4; ++r) {
            int o = orow + r;
            if (o < OFFC_)
                offl[o][lane & 15] = acc[r] + b_off[o];
        }
    }
    __syncthreads();

    // ---- phase 2: positions/weights for 16 px x 9 taps (144 tasks) ----
    if (tid < 16*KK_) {
        int p = tid / KK_, kk = tid % KK_;
        int wo = wo0 + p;
        float dy = offl[2*kk  ][p];
        float dx = offl[2*kk+1][p];
        float py = (float)(ho - 1 + kk/3) + dy;
        float px = (float)(wo - 1 + kk%3) + dx;
        float fy = floorf(py), fx = floorf(px);
        int y0 = (int)fy, x0 = (int)fx;
        float ly = py - fy, lx = px - fx;
        int y1 = y0 + 1, x1 = x0 + 1;
        float my0 = ((unsigned)y0 < H_) ? 1.f : 0.f;
        float my1 = ((unsigned)y1 < H_) ? 1.f : 0.f;
        float mx0 = ((unsigned)x0 < W_) ? 1.f : 0.f;
        float mx1 = ((unsigned)x1 < W_) ? 1.f : 0.f;
        int y0c = min(max(y0,0),H_-1), y1c = min(max(y1,0),H_-1);
        int x0c = min(max(x0,0),W_-1), x1c = min(max(x1,0),W_-1);
        posf[p][kk][0] = (1.f-ly)*(1.f-lx)*my0*mx0;
        posf[p][kk][1] = (1.f-ly)*lx*my0*mx1;
        posf[p][kk][2] = ly*(1.f-lx)*my1*mx0;
        posf[p][kk][3] = ly*lx*my1*mx1;
        posi[p][kk][0] = (y0c*W_ + x0c)*128;    // byte offsets into NHWC fp16
        posi[p][kk][1] = (y0c*W_ + x1c)*128;
        posi[p][kk][2] = (y1c*W_ + x0c)*128;
        posi[p][kk][3] = (y1c*W_ + x1c)*128;
    }
    __syncthreads();

    // ---- phase 3: bilinear gather, 8 ch (16 B) per task, packed fp16 blend ----
    {
        int cg8 = tid & 7, p = (tid >> 3) & 15, kh = tid >> 7;
        int ph = p & 7;
        char* vb = val + p * VSB;
        int nkk = kh ? 4 : 5;
#pragma unroll 5
        for (int i = 0; i < nkk; ++i) {
            int kk = 2*i + kh;
            float4 wv = *(const float4*)posf[p][kk];
            int4   av = *(const int4*)posi[p][kk];
            h8 c0 = *(const h8*)(xbc + av.x + cg8*16);
            h8 c1 = *(const h8*)(xbc + av.y + cg8*16);
            h8 c2 = *(const h8*)(xbc + av.z + cg8*16);
            h8 c3 = *(const h8*)(xbc + av.w + cg8*16);
            _Float16 h00 = (_Float16)wv.x, h01 = (_Float16)wv.y;
            _Float16 h10 = (_Float16)wv.z, h11 = (_Float16)wv.w;
            h8 w00v = {h00,h00,h00,h00,h00,h00,h00,h00};
            h8 w01v = {h01,h01,h01,h01,h01,h01,h01,h01};
            h8 w10v = {h10,h10,h10,h10,h10,h10,h10,h10};
            h8 w11v = {h11,h11,h11,h11,h11,h11,h11,h11};
            h8 r = c0*w00v + c1*w01v + c2*w10v + c3*w11v;
            int g8 = kk*8 + cg8;
            *(h8*)(vb + ((g8 ^ ph) << 4)) = r;
        }
    }
    __syncthreads();

    // ---- phase 4: 18 MFMA, wave w owns output channels w*16..w*16+15 ----
    {
        h8 afr[18];
        const _Float16* wp = wb + ((wave*18)*64 + lane)*8;
#pragma unroll
        for (int t = 0; t < 18; ++t) afr[t] = *(const h8*)(wp + t*512);
        f32x4 acc = {0.f,0.f,0.f,0.f};
        const char* vb = val + (lane & 15) * VSB;
        int gk = (lane >> 4) & 3;
        int ph = (lane & 15) & 7;
#pragma unroll
        for (int t = 0; t < 18; ++t) {
            h8 bfr = *(const h8*)(vb + (((t*4 + gk) ^ ph) << 4));
            acc = __builtin_amdgcn_mfma_f32_16x16x32_f16(afr[t], bfr, acc, 0, 0, 0);
        }
        int orow = wave*16 + gk*4;
        int wo = wo0 + (lane & 15);
#pragma unroll
        for (int r = 0; r < 4; ++r) {
            int o = orow + r;
            out[((b*O_ + o)*H_ + ho)*W_ + wo] = acc[r] + b_dcn[o];
        }
    }
}

extern "C" void kernel_launch(void* const* d_in, const int* in_sizes, int n_in,
                              void* d_out, int out_size, void* d_ws, size_t ws_size,
                              hipStream_t stream) {
    const float* x     = (const float*)d_in[0];
    const float* w_off = (const float*)d_in[1];
    const float* b_off = (const float*)d_in[2];
    const float* w_dcn = (const float*)d_in[3];
    const float* b_dcn = (const float*)d_in[4];
    float* out = (float*)d_out;

    char* ws = (char*)d_ws;
    _Float16* xt   = (_Float16*)ws;                          // 8,388,608 B
    _Float16* wb   = (_Float16*)(ws + 8388608);              // 73,728 B
    _Float16* wboff = wb + O_*576;                           // 36,864 B

    k_pre<<<728, 256, 0, stream>>>(x, w_dcn, w_off, xt, wb, wboff);
    k_fused<<<B_ * H_ * 8, 256, 0, stream>>>(xt, wb, wboff, b_off, b_dcn, out);
}

// Round 6
// 42.371 us; speedup vs baseline: 10.8983x; 1.0929x over previous
//
#include <hip/hip_runtime.h>

#define B_ 4
#define C_ 64
#define H_ 128
#define W_ 128
#define O_ 64
#define KK_ 9
#define OFFC_ 18
#define HW_ (H_*W_)
#define VSB 1152   // val row stride in bytes (576 fp16)

typedef __attribute__((ext_vector_type(8))) _Float16 h8;
typedef __attribute__((ext_vector_type(4))) _Float16 h4;
typedef __attribute__((ext_vector_type(4))) float f32x4;

// ---------- kernel 1: transpose x NCHW fp32 -> NHWC fp16, + weight prep ----------
// blocks 0..511: transpose one (b,h) row. blocks 512..727: pack weights.
__global__ __launch_bounds__(256) void k_pre(
    const float* __restrict__ x, const float* __restrict__ w_dcn,
    const float* __restrict__ w_off, _Float16* __restrict__ xt,
    _Float16* __restrict__ wb, _Float16* __restrict__ wboff)
{
    __shared__ float tile[C_][133];
    int blk = blockIdx.x;
    if (blk < 512) {
        const float* xp = x + (size_t)(blk >> 7) * C_ * HW_ + (blk & 127) * W_;
#pragma unroll
        for (int i = 0; i < 8; ++i) {
            int idx = threadIdx.x + i * 256;     // 0..2047 float4 slots
            int c = idx >> 5, w4 = idx & 31;
            float4 v = *(const float4*)(xp + c * HW_ + w4 * 4);
            tile[c][w4*4+0] = v.x; tile[c][w4*4+1] = v.y;
            tile[c][w4*4+2] = v.z; tile[c][w4*4+3] = v.w;
        }
        __syncthreads();
        _Float16* op = xt + (size_t)blk * (W_ * C_);
#pragma unroll
        for (int i = 0; i < 8; ++i) {
            int idx = threadIdx.x + i * 256;     // 0..2047 h4 slots
            int w = idx >> 4, c4 = idx & 15;
            h4 o;
            o.x = (_Float16)tile[c4*4+0][w]; o.y = (_Float16)tile[c4*4+1][w];
            o.z = (_Float16)tile[c4*4+2][w]; o.w = (_Float16)tile[c4*4+3][w];
            *(h4*)(op + w*64 + c4*4) = o;
        }
    } else {
        int i = (blk - 512) * 256 + threadIdx.x;
        if (i < O_ * 576) {
            int j = i & 7, l = (i >> 3) & 63, t = (i >> 9) % 18, ot = i / (18*512);
            int k = t*32 + ((l>>4)&3)*8 + j;
            int o = ot*16 + (l & 15);
            int kk = k >> 6, c = k & 63;
            wb[i] = (_Float16)w_dcn[(o*64 + c)*9 + kk];
        }
        int i2 = i - O_*576;
        if (i2 >= 0 && i2 < 32*576) {
            int j = i2 & 7, l = (i2 >> 3) & 63, t = (i2 >> 9) % 18, mt = i2 / (18*512);
            int k = t*32 + ((l>>4)&3)*8 + j;
            int o = mt*16 + (l & 15);
            int kk = k >> 6, c = k & 63;
            wboff[i2] = (o < OFFC_) ? (_Float16)w_off[(o*64 + c)*9 + kk] : (_Float16)0.f;
        }
    }
}

// ---------- kernel 2: fused offset-conv + deformable conv, 32-px blocks ----------
// grid = B*H*4 = 2048, XCD-swizzled: each XCD owns 256 consecutive blocks
// (64 rows of one batch, xt slice ~1 MB -> L2-resident).
__global__ __launch_bounds__(256) void k_fused(
    const _Float16* __restrict__ xt, const _Float16* __restrict__ wb,
    const _Float16* __restrict__ wboff, const float* __restrict__ b_off,
    const float* __restrict__ b_dcn, float* __restrict__ out)
{
    __shared__ __align__(16) char val2[2][16 * VSB];    // 36864 B
    __shared__ __align__(16) float offl[OFFC_][32];     // 2304 B
    __shared__ __align__(16) float posf[32][KK_][4];    // 4608 B
    __shared__ __align__(16) int   posi[32][KK_][4];    // 4608 B

    int tid = threadIdx.x;
    int d = blockIdx.x;
    int blk = (d & 7) * 256 + (d >> 3);   // XCD-contiguous chunks
    int wt2 = blk & 3, ho = (blk >> 2) & 127, b = blk >> 9;
    int wo0 = wt2 * 32;
    int wave = tid >> 6, lane = tid & 63;
    int mt = wave >> 1;          // M-tile for offset MFMA
    int rg_m = wave & 1;         // px region for offset MFMA
    const char* xbc = (const char*)xt + (size_t)b * HW_ * 128;

    // ---- phase 0: regular im2col gather for offset conv -> val2 ----
    {
        int cg8 = tid & 7, px32 = tid >> 3;
        int rg_f = px32 >> 4, p = px32 & 15, ph = p & 7;
        char* vb = &val2[rg_f][0] + p * VSB;
        int wo = wo0 + px32;
#pragma unroll 3
        for (int kk = 0; kk < KK_; ++kk) {
            int y = ho + kk/3 - 1;
            int xx = wo + kk%3 - 1;
            h8 v = {0,0,0,0,0,0,0,0};
            if ((unsigned)y < H_ && (unsigned)xx < W_)
                v = *(const h8*)(xbc + (y*W_ + xx)*128 + cg8*16);
            int g8 = kk*8 + cg8;
            *(h8*)(vb + ((g8 ^ ph) << 4)) = v;
        }
    }
    __syncthreads();

    // ---- phase 1: offset MFMA, wave=(mt,rg) -> offl ----
    {
        h8 afr[18];
        const _Float16* wp = wboff + ((mt*18)*64 + lane)*8;
#pragma unroll
        for (int t = 0; t < 18; ++t) afr[t] = *(const h8*)(wp + t*512);
        f32x4 acc = {0.f,0.f,0.f,0.f};
        const char* vb = &val2[rg_m][0] + (lane & 15) * VSB;
        int gk = (lane >> 4) & 3;
        int ph = (lane & 15) & 7;
#pragma unroll
        for (int t = 0; t < 18; ++t) {
            h8 bfr = *(const h8*)(vb + (((t*4 + gk) ^ ph) << 4));
            acc = __builtin_amdgcn_mfma_f32_16x16x32_f16(afr[t], bfr, acc, 0, 0, 0);
        }
        int orow = mt*16 + gk*4;
#pragma unroll
        for (int r = 0; r < 4; ++r) {
            int o = orow + r;
            if (o < OFFC_)
                offl[o][rg_m*16 + (lane & 15)] = acc[r] + b_off[o];
        }
    }
    __syncthreads();

    // ---- phase 2: positions/weights for 32 px x 9 taps (288 tasks) ----
#pragma unroll
    for (int i = 0; i < 2; ++i) {
        int task = tid + i*256;
        if (task < 32*KK_) {
            int p = task / KK_, kk = task % KK_;
            int wo = wo0 + p;
            float dy = offl[2*kk  ][p];
            float dx = offl[2*kk+1][p];
            float py = (float)(ho - 1 + kk/3) + dy;
            float px = (float)(wo - 1 + kk%3) + dx;
            float fy = floorf(py), fx = floorf(px);
            int y0 = (int)fy, x0 = (int)fx;
            float ly = py - fy, lx = px - fx;
            int y1 = y0 + 1, x1 = x0 + 1;
            float my0 = ((unsigned)y0 < H_) ? 1.f : 0.f;
            float my1 = ((unsigned)y1 < H_) ? 1.f : 0.f;
            float mx0 = ((unsigned)x0 < W_) ? 1.f : 0.f;
            float mx1 = ((unsigned)x1 < W_) ? 1.f : 0.f;
            int y0c = min(max(y0,0),H_-1), y1c = min(max(y1,0),H_-1);
            int x0c = min(max(x0,0),W_-1), x1c = min(max(x1,0),W_-1);
            posf[p][kk][0] = (1.f-ly)*(1.f-lx)*my0*mx0;
            posf[p][kk][1] = (1.f-ly)*lx*my0*mx1;
            posf[p][kk][2] = ly*(1.f-lx)*my1*mx0;
            posf[p][kk][3] = ly*lx*my1*mx1;
            posi[p][kk][0] = (y0c*W_ + x0c)*128;    // byte offsets, NHWC fp16
            posi[p][kk][1] = (y0c*W_ + x1c)*128;
            posi[p][kk][2] = (y1c*W_ + x0c)*128;
            posi[p][kk][3] = (y1c*W_ + x1c)*128;
        }
    }
    __syncthreads();

    // ---- phase 3: bilinear gather, 8 ch (16 B) per task, packed fp16 blend ----
    {
        int cg8 = tid & 7, p = (tid >> 3) & 31;
        int ph = p & 7;
        char* vb = &val2[p >> 4][0] + (p & 15) * VSB;
#pragma unroll 3
        for (int kk = 0; kk < KK_; ++kk) {
            float4 wv = *(const float4*)posf[p][kk];
            int4   av = *(const int4*)posi[p][kk];
            h8 c0 = *(const h8*)(xbc + av.x + cg8*16);
            h8 c1 = *(const h8*)(xbc + av.y + cg8*16);
            h8 c2 = *(const h8*)(xbc + av.z + cg8*16);
            h8 c3 = *(const h8*)(xbc + av.w + cg8*16);
            _Float16 h00 = (_Float16)wv.x, h01 = (_Float16)wv.y;
            _Float16 h10 = (_Float16)wv.z, h11 = (_Float16)wv.w;
            h8 w00v = {h00,h00,h00,h00,h00,h00,h00,h00};
            h8 w01v = {h01,h01,h01,h01,h01,h01,h01,h01};
            h8 w10v = {h10,h10,h10,h10,h10,h10,h10,h10};
            h8 w11v = {h11,h11,h11,h11,h11,h11,h11,h11};
            h8 r = c0*w00v + c1*w01v + c2*w10v + c3*w11v;
            int g8 = kk*8 + cg8;
            *(h8*)(vb + ((g8 ^ ph) << 4)) = r;
        }
    }
    __syncthreads();

    // ---- phase 4: deform MFMA, wave w owns ch w*16..w*16+15, both regions ----
    {
        h8 afr[18];
        const _Float16* wp = wb + ((wave*18)*64 + lane)*8;
#pragma unroll
        for (int t = 0; t < 18; ++t) afr[t] = *(const h8*)(wp + t*512);
        int gk = (lane >> 4) & 3;
        int ph = (lane & 15) & 7;
        int orow = wave*16 + gk*4;
#pragma unroll
        for (int rg = 0; rg < 2; ++rg) {
            f32x4 acc = {0.f,0.f,0.f,0.f};
            const char* vb = &val2[rg][0] + (lane & 15) * VSB;
#pragma unroll
            for (int t = 0; t < 18; ++t) {
                h8 bfr = *(const h8*)(vb + (((t*4 + gk) ^ ph) << 4));
                acc = __builtin_amdgcn_mfma_f32_16x16x32_f16(afr[t], bfr, acc, 0, 0, 0);
            }
            int wo = wo0 + rg*16 + (lane & 15);
#pragma unroll
            for (int r = 0; r < 4; ++r) {
                int o = orow + r;
                out[((b*O_ + o)*H_ + ho)*W_ + wo] = acc[r] + b_dcn[o];
            }
        }
    }
}

extern "C" void kernel_launch(void* const* d_in, const int* in_sizes, int n_in,
                              void* d_out, int out_size, void* d_ws, size_t ws_size,
                              hipStream_t stream) {
    const float* x     = (const float*)d_in[0];
    const float* w_off = (const float*)d_in[1];
    const float* b_off = (const float*)d_in[2];
    const float* w_dcn = (const float*)d_in[3];
    const float* b_dcn = (const float*)d_in[4];
    float* out = (float*)d_out;

    char* ws = (char*)d_ws;
    _Float16* xt   = (_Float16*)ws;                          // 8,388,608 B
    _Float16* wb   = (_Float16*)(ws + 8388608);              // 73,728 B
    _Float16* wboff = wb + O_*576;                           // 36,864 B

    k_pre<<<728, 256, 0, stream>>>(x, w_dcn, w_off, xt, wb, wboff);
    k_fused<<<B_ * H_ * 4, 256, 0, stream>>>(xt, wb, wboff, b_off, b_dcn, out);
}